// Round 8
// baseline (89.524 us; speedup 1.0000x reference)
//
#include <hip/hip_runtime.h>
#include <hip/hip_bf16.h>
#include <math.h>

#define BATCH 4096
#define DIM 128
#define TWO_B 8192
// reps scaled by sqrt(2*log2(e)) so fp8 MFMA acc = 2*log2(e)*sim, and
// exp(sim/TEMP) = exp(2*sim) = exp2(acc) -> single native v_exp_f32.
#define SCALE 1.69864374f

typedef float floatx4 __attribute__((ext_vector_type(4)));
typedef int   intx4  __attribute__((ext_vector_type(4)));
typedef long  longx2 __attribute__((ext_vector_type(2)));

__device__ __forceinline__ longx2 as_l2(intx4 v) {
    union { intx4 a; longx2 b; } u; u.a = v; return u.b;
}
__device__ __forceinline__ unsigned char to_fp8(float v) {
    return (unsigned char)(__builtin_amdgcn_cvt_pk_fp8_f32(v, v, 0, false) & 0xff);
}

// FP8 fragment-native blocked layout (byte address):
//   addr(r,k) = (r>>4)*2048 + (k>>6)*1024 + ((k>>3)&3)*256 + (r&15)*16
//             + ((k>>5)&1)*8 + (k&7)
// A wave's 16-lane-group load at q*256 + lr*16 of 16B yields exactly the
// mfma_f32_16x16x32_fp8 A/B fragments for two K=32 chunks (1KB/instruction).

// Kernel 1: L2-normalize (pre-scaled) -> fp8 blocked reps; fp32 positives.
// Store path: LDS-staged, then one fully-coalesced 4B/thread store hitting
// only FULL 64B lines (the 4 consecutive rows of this block tile the lines)
// -- no partial-line RMW against the poisoned workspace.
__global__ __launch_bounds__(256) void norm_kernel(const float* __restrict__ p1,
                                                   const float* __restrict__ p2,
                                                   unsigned char* __restrict__ repsF,
                                                   float* __restrict__ pos,
                                                   float* __restrict__ out) {
    __shared__ unsigned char stage[2][8][64];   // [proj][chunk][slot*16+inner]
    int tid = threadIdx.x;
    int w = tid >> 6, l = tid & 63;
    int b0 = blockIdx.x * 4;
    int b = b0 + w;
    const float* r1 = p1 + (size_t)b * DIM;
    const float* r2 = p2 + (size_t)b * DIM;
    float x0 = r1[l], x1 = r1[l + 64];
    float y0 = r2[l], y1 = r2[l + 64];
    float s1 = x0 * x0 + x1 * x1;
    float s2 = y0 * y0 + y1 * y1;
    float s12 = x0 * y0 + x1 * y1;
    #pragma unroll
    for (int off = 32; off; off >>= 1) {
        s1  += __shfl_xor(s1, off);
        s2  += __shfl_xor(s2, off);
        s12 += __shfl_xor(s12, off);
    }
    float n1 = fmaxf(sqrtf(s1), 1e-12f);
    float n2 = fmaxf(sqrtf(s2), 1e-12f);
    float i1 = SCALE / n1;
    float i2 = SCALE / n2;

    // k = l -> chunk (l>>3)&3 ; k = l+64 -> chunk 4+((l>>3)&3); same inner.
    int cc = (l >> 3) & 3;
    int inner = ((l >> 5) & 1) * 8 + (l & 7);
    stage[0][cc    ][w * 16 + inner] = to_fp8(x0 * i1);
    stage[0][cc + 4][w * 16 + inner] = to_fp8(x1 * i1);
    stage[1][cc    ][w * 16 + inner] = to_fp8(y0 * i2);
    stage[1][cc + 4][w * 16 + inner] = to_fp8(y1 * i2);

    if (l == 0) {
        pos[b] = s12 / (n1 * n2);            // exact fp32 positive (unscaled)
        if (b == 0) out[0] = 0.0f;
    }
    __syncthreads();

    // Coalesced writeback: 256 threads x 4B. Rows b0..b0+3 occupy slots
    // (b0&15)..+3 => one full 64B line per chunk region.
    int which = tid >> 7, u = tid & 127;
    int ch = u >> 4, l16 = u & 15;
    int rowbase = which ? (b0 + BATCH) : b0;
    size_t gbyte = (size_t)(rowbase >> 4) * 2048 + ch * 256 + (b0 & 15) * 16 + l16 * 4;
    *(int*)(repsF + gbyte) = ((const int*)&stage[which][ch][0])[l16];
}

// Kernel 2: 128x128 pair-region per block, triangular TM<=TN (grid 65x32,
// zero idle). 4 waves 2x2; wave (wm,wn) owns 64x64 tile pair (tm<=tn);
// mirror quadrant of diag region skipped. All-K fp8 fragments resident,
// single MFMA pass, bare-exp2 epilogue. Marginal writeback is LDS-staged
// per wave, then ONE 64-lane contiguous 256B store per marginal (full
// 64B lines, no RMW, fast end-of-wave drain). No barriers, no atomics:
// part[k][r] written exactly once.
__global__ __launch_bounds__(256, 3) void sim_kernel(const unsigned char* __restrict__ repsF,
                                                     float* __restrict__ part) {
    __shared__ float stage[4][64];       // per-wave slice, wave-local (no barrier)
    int tid = threadIdx.x;
    int wid = tid >> 6, lane = tid & 63;
    int wm = wid >> 1, wn = wid & 1;
    int lr = lane & 15, q = lane >> 4;
    int r = blockIdx.y;                  // [0,32)
    int c = blockIdx.x;                  // [0,65)
    int TM, TN;
    if (c < 64 - r) { TM = r;      TN = r + c; }
    else            { TM = 63 - r; TN = TM + (c - (64 - r)); }
    if (TM == TN && wm == 1 && wn == 0) return;   // mirror quadrant
    int tm = 2 * TM + wm, tn = 2 * TN + wn;       // tm <= tn guaranteed
    bool diag = (tm == tn);

    const char* base = (const char*)repsF;
    int lofs = q * 256 + lr * 16;
    const char* ab = base + tm * 8192 + lofs;
    const char* bb = base + tn * 8192 + lofs;

    longx2 aF[4][2], bF[4][2];           // [mi][h]: .x = chunk 2h, .y = 2h+1
    #pragma unroll
    for (int mi = 0; mi < 4; ++mi)
        #pragma unroll
        for (int h = 0; h < 2; ++h) {
            aF[mi][h] = as_l2(*(const intx4*)(ab + mi * 2048 + h * 1024));
            bF[mi][h] = as_l2(*(const intx4*)(bb + mi * 2048 + h * 1024));
        }

    floatx4 acc[4][4] = {};
    #pragma unroll
    for (int ck = 0; ck < 4; ++ck) {     // K=32 chunks
        int h = ck >> 1, sel = ck & 1;
        #pragma unroll
        for (int mi = 0; mi < 4; ++mi)
            #pragma unroll
            for (int ni = 0; ni < 4; ++ni)
                acc[mi][ni] = __builtin_amdgcn_mfma_f32_16x16x32_fp8_fp8(
                    aF[mi][h][sel], bF[ni][h][sel], acc[mi][ni], 0, 0, 0);
    }

    // Epilogue. C/D layout: col = lr + 16*ni, row = q*4 + reg + 16*mi.
    float cs[4] = {0.0f, 0.0f, 0.0f, 0.0f};
    #pragma unroll
    for (int mi = 0; mi < 4; ++mi) {
        float rp[4];
        #pragma unroll
        for (int reg = 0; reg < 4; ++reg) {
            float e0 = __builtin_amdgcn_exp2f(acc[mi][0][reg]);
            float e1 = __builtin_amdgcn_exp2f(acc[mi][1][reg]);
            float e2 = __builtin_amdgcn_exp2f(acc[mi][2][reg]);
            float e3 = __builtin_amdgcn_exp2f(acc[mi][3][reg]);
            if (diag && (q * 4 + reg) == lr) {
                if (mi == 0) e0 = 0.0f;
                if (mi == 1) e1 = 0.0f;
                if (mi == 2) e2 = 0.0f;
                if (mi == 3) e3 = 0.0f;
            }
            cs[0] += e0; cs[1] += e1; cs[2] += e2; cs[3] += e3;
            rp[reg] = (e0 + e1) + (e2 + e3);
        }
        #pragma unroll
        for (int mask = 1; mask < 16; mask <<= 1)
            #pragma unroll
            for (int reg = 0; reg < 4; ++reg)
                rp[reg] += __shfl_xor(rp[reg], mask);
        if (lr == 0) {
            #pragma unroll
            for (int reg = 0; reg < 4; ++reg)
                stage[wid][mi * 16 + q * 4 + reg] = rp[reg];
        }
    }
    // One contiguous 256B wave store (4 full lines) for the row-marginal.
    part[(size_t)tn * TWO_B + tm * 64 + lane] = stage[wid][lane];

    if (!diag) {
        #pragma unroll
        for (int ni = 0; ni < 4; ++ni) {
            cs[ni] += __shfl_xor(cs[ni], 16);
            cs[ni] += __shfl_xor(cs[ni], 32);
        }
        if (q == 0) {
            #pragma unroll
            for (int ni = 0; ni < 4; ++ni)
                stage[wid][ni * 16 + lr] = cs[ni];
        }
        part[(size_t)tm * TWO_B + tn * 64 + lane] = stage[wid][lane];
    }
}

// Kernel 3: denom[r] = sum_k part[k][r]; loss = mean(log(denom) - 2*pos).
__global__ __launch_bounds__(128) void reduce_kernel(const float* __restrict__ part,
                                                     const float* __restrict__ pos,
                                                     float* __restrict__ out) {
    int tid = threadIdx.x;
    int rr = blockIdx.x * 128 + tid;
    float s0 = 0.0f, s1 = 0.0f, s2 = 0.0f, s3 = 0.0f;
    #pragma unroll 8
    for (int k = 0; k < 128; k += 4) {
        s0 += part[(size_t)(k + 0) * TWO_B + rr];
        s1 += part[(size_t)(k + 1) * TWO_B + rr];
        s2 += part[(size_t)(k + 2) * TWO_B + rr];
        s3 += part[(size_t)(k + 3) * TWO_B + rr];
    }
    float v = __logf((s0 + s1) + (s2 + s3)) - 2.0f * pos[rr & (BATCH - 1)];
    #pragma unroll
    for (int off = 32; off; off >>= 1) v += __shfl_xor(v, off);
    __shared__ float sred[2];
    int lane = tid & 63, wid = tid >> 6;
    if (lane == 0) sred[wid] = v;
    __syncthreads();
    if (tid == 0)
        atomicAdd(out, (sred[0] + sred[1]) * (1.0f / TWO_B));
}

extern "C" void kernel_launch(void* const* d_in, const int* in_sizes, int n_in,
                              void* d_out, int out_size, void* d_ws, size_t ws_size,
                              hipStream_t stream) {
    const float* p1 = (const float*)d_in[0];
    const float* p2 = (const float*)d_in[1];
    float* out = (float*)d_out;

    char* ws = (char*)d_ws;
    unsigned char* repsF = (unsigned char*)ws;                 // 1 MB
    float* pos  = (float*)(ws + (size_t)TWO_B * DIM);          // 16 KB
    float* part = pos + BATCH;                                 // 4 MB

    norm_kernel<<<BATCH / 4, 256, 0, stream>>>(p1, p2, repsF, pos, out);
    sim_kernel<<<dim3(65, 32), 256, 0, stream>>>(repsF, part);
    reduce_kernel<<<TWO_B / 128, 128, 0, stream>>>(part, pos, out);
}